// Round 1
// baseline (1275.294 us; speedup 1.0000x reference)
//
#include <hip/hip_runtime.h>
#include <stdint.h>

// ---------------- problem constants ----------------
#define T_TOK 8192
#define D_DIM 2048
#define H_DIM 2048
#define NEXP 8
// GEMM tiling (m97-class structure: 128x128 tile, BK=64, 4 waves)
#define BM 128
#define BN 128
#define BK 64
// worst-case M-tiles: sum_e ceil(cnt_e/128) <= 16384/128 + 8 = 136
#define MAXMT 136
#define MAXSLOTS (MAXMT * BM)   // 17408 padded routed slots

typedef __attribute__((ext_vector_type(8))) short bf16x8;
typedef __attribute__((ext_vector_type(4))) float f32x4;

__device__ __forceinline__ unsigned short f2bf(float f) {
  uint32_t u = __float_as_uint(f);
  u += 0x7fffu + ((u >> 16) & 1u);   // round-to-nearest-even
  return (unsigned short)(u >> 16);
}
__device__ __forceinline__ float bf2f(uint32_t ubits16) {
  return __uint_as_float(ubits16 << 16);
}
__device__ __forceinline__ uint32_t pack2(float a, float b) {
  return (uint32_t)f2bf(a) | ((uint32_t)f2bf(b) << 16);
}
__device__ __forceinline__ void gload_lds16(const unsigned short* g, unsigned short* l) {
  __builtin_amdgcn_global_load_lds(
      (const __attribute__((address_space(1))) unsigned int*)g,
      (__attribute__((address_space(3))) unsigned int*)l, 16, 0, 0);
}

// ---------------- init: zero counters, perm_token = -1 ----------------
__global__ void init_kernel(int* __restrict__ perm_token, int* __restrict__ ctr) {
  int i = blockIdx.x * 256 + threadIdx.x;
  if (i < MAXSLOTS) perm_token[i] = -1;
  if (i < 16) ctr[i] = 0;  // ctr[0..7]=cnt, ctr[8..15]=cursor
}

// ---------------- router: f64 logits, top-2, softmax scores ----------------
// f64 accumulation so top-2 selection agrees with the numpy reference even at
// near-ties (f32 reordering noise ~1e-6 would risk expert swaps; f64 ~1e-13).
__global__ __launch_bounds__(256) void router_kernel(
    const float* __restrict__ x, const float* __restrict__ gate_w,
    int* __restrict__ top_idx, float* __restrict__ top_score,
    int* __restrict__ cnt) {
  __shared__ float gw[NEXP * D_DIM];  // 64 KB
  for (int i = threadIdx.x; i < NEXP * D_DIM / 4; i += 256)
    ((float4*)gw)[i] = ((const float4*)gate_w)[i];
  __syncthreads();

  const int lane = threadIdx.x & 63, wid = threadIdx.x >> 6;
  for (int sub = 0; sub < 4; ++sub) {
    const int t = blockIdx.x * 16 + wid * 4 + sub;
    double acc[NEXP] = {};
    for (int i = 0; i < D_DIM / 64; ++i) {
      const int d = i * 64 + lane;
      const float xv = x[(size_t)t * D_DIM + d];
#pragma unroll
      for (int e = 0; e < NEXP; ++e)
        acc[e] += (double)xv * (double)gw[e * D_DIM + d];
    }
#pragma unroll
    for (int e = 0; e < NEXP; ++e) {
      double v = acc[e];
      for (int o = 32; o >= 1; o >>= 1) v += __shfl_xor(v, o, 64);
      acc[e] = v;
    }
    if (lane == 0) {
      int i0 = 0;
      for (int e = 1; e < NEXP; ++e) if (acc[e] > acc[i0]) i0 = e;
      int i1 = (i0 == 0) ? 1 : 0;
      for (int e = 0; e < NEXP; ++e) if (e != i0 && acc[e] > acc[i1]) i1 = e;
      const double m = acc[i0];
      double den = 0.0;
      for (int e = 0; e < NEXP; ++e) den += exp(acc[e] - m);
      top_idx[t * 2 + 0] = i0;
      top_idx[t * 2 + 1] = i1;
      top_score[t * 2 + 0] = (float)(exp(acc[i0] - m) / den);
      top_score[t * 2 + 1] = (float)(exp(acc[i1] - m) / den);
      atomicAdd(&cnt[i0], 1);
      atomicAdd(&cnt[i1], 1);
    }
  }
}

// ---------------- offsets + tile tables (1 thread; E=8, <=136 tiles) --------
__global__ void offsets_kernel(const int* __restrict__ cnt, int* __restrict__ seg_off,
                               int* __restrict__ tile_e, int* __restrict__ tile_row0,
                               int* __restrict__ nMt) {
  if (threadIdx.x == 0 && blockIdx.x == 0) {
    int off = 0, idx = 0;
    for (int e = 0; e < NEXP; ++e) {
      seg_off[e] = off;
      const int nt = (cnt[e] + BM - 1) / BM;
      for (int j = 0; j < nt; ++j) { tile_e[idx] = e; tile_row0[idx] = off + j * BM; ++idx; }
      off += nt * BM;
    }
    *nMt = idx;
  }
}

// ---------------- assign routed slots ----------------
__global__ void assign_kernel(const int* __restrict__ top_idx, const float* __restrict__ top_score,
                              const int* __restrict__ seg_off, int* __restrict__ cursor,
                              int* __restrict__ perm_token, float* __restrict__ perm_score,
                              int* __restrict__ perm_slot) {
  const int t = blockIdx.x * 256 + threadIdx.x;
  if (t >= T_TOK) return;
#pragma unroll
  for (int k = 0; k < 2; ++k) {
    const int e = top_idx[t * 2 + k];
    const int pos = seg_off[e] + atomicAdd(&cursor[e], 1);
    perm_token[pos] = t;
    perm_score[pos] = top_score[t * 2 + k];
    perm_slot[pos] = k;
  }
}

// ---------------- gather: xg[p] = bf16(x[token[p]] * score[p]) --------------
__global__ __launch_bounds__(256) void gather_kernel(
    const float* __restrict__ x, const int* __restrict__ perm_token,
    const float* __restrict__ perm_score, unsigned short* __restrict__ xg) {
  const int p = blockIdx.x;
  const int t = perm_token[p];
  unsigned short* dst = xg + (size_t)p * D_DIM + threadIdx.x * 8;
  if (t < 0) {
    *(uint4*)dst = make_uint4(0u, 0u, 0u, 0u);  // pad rows -> exact zeros
    return;
  }
  const float c = perm_score[p];
  const float4* src = (const float4*)(x + (size_t)t * D_DIM + threadIdx.x * 8);
  const float4 v0 = src[0], v1 = src[1];
  uint4 o;
  o.x = pack2(v0.x * c, v0.y * c);
  o.y = pack2(v0.z * c, v0.w * c);
  o.z = pack2(v1.x * c, v1.y * c);
  o.w = pack2(v1.z * c, v1.w * c);
  *(uint4*)dst = o;
}

// ---------------- weight f32 -> bf16 conversion ----------------
__global__ __launch_bounds__(256) void wconv_kernel(const float* __restrict__ src,
                                                    unsigned short* __restrict__ dst, int n8) {
  const int stride = gridDim.x * blockDim.x;
  for (int i = blockIdx.x * blockDim.x + threadIdx.x; i < n8; i += stride) {
    const float4* s = (const float4*)(src + (size_t)i * 8);
    const float4 a = s[0], b = s[1];
    uint4 o;
    o.x = pack2(a.x, a.y); o.y = pack2(a.z, a.w);
    o.z = pack2(b.x, b.y); o.w = pack2(b.z, b.w);
    *(uint4*)(dst + (size_t)i * 8) = o;
  }
}

// ---------------- grouped GEMM1: h = silu(xg @ w1^T) * (xg @ w3^T) ----------
// 128x128 tile, BK=64, 4 waves (2x2), dual-B sharing the A tile.
// LDS tiles are XOR-swizzled (byte ^= (row&7)<<4) to break the 16-way bank
// conflict of 128B rows; global_load_lds writes linearly so the *source*
// address carries the inverse swizzle (rule #21: both-sides-or-neither).
__global__ __launch_bounds__(256, 2) void gemm1_kernel(
    const unsigned short* __restrict__ xg, const unsigned short* __restrict__ wb1,
    const unsigned short* __restrict__ wb3, unsigned short* __restrict__ hbuf,
    const int* __restrict__ tile_e, const int* __restrict__ tile_row0,
    const int* __restrict__ nMt) {
  if ((int)blockIdx.x >= *nMt) return;
  __shared__ unsigned short As[BM * BK];
  __shared__ unsigned short B1s[BN * BK];
  __shared__ unsigned short B2s[BN * BK];

  const int e = tile_e[blockIdx.x];
  const int row0 = tile_row0[blockIdx.x];
  const int n0 = blockIdx.y * BN;

  const int tid = threadIdx.x;
  const int lane = tid & 63, wid = tid >> 6;
  const int wm = wid >> 1, wn = wid & 1;
  const int l15 = lane & 15, lk = lane >> 4;

  int srow[4], scol[4];
#pragma unroll
  for (int i = 0; i < 4; ++i) {
    const int fo = i * 4096 + wid * 1024 + lane * 16;  // linear byte in 16KB tile
    const int r = fo >> 7;
    const int cbl = (fo & 127) ^ ((r & 7) << 4);       // inverse-swizzled source col
    srow[i] = r; scol[i] = cbl >> 1;
  }
  const unsigned short* gA = xg + (size_t)row0 * D_DIM;
  const unsigned short* gB1 = wb1 + ((size_t)e * H_DIM + n0) * D_DIM;
  const unsigned short* gB2 = wb3 + ((size_t)e * H_DIM + n0) * D_DIM;

  // ds_read byte offsets; addr(kk) = off ^ (kk<<6) thanks to disjoint XOR bits
  int aOff[4], bOff[4];
#pragma unroll
  for (int f = 0; f < 4; ++f) {
    const int ra = wm * 64 + f * 16 + l15, sa = (ra & 7) << 4;
    aOff[f] = ra * 128 + ((lk * 16) ^ (sa & 0x30)) + (sa & 0x40);
    const int rb = wn * 64 + f * 16 + l15, sb = (rb & 7) << 4;
    bOff[f] = rb * 128 + ((lk * 16) ^ (sb & 0x30)) + (sb & 0x40);
  }

  f32x4 acc1[4][4] = {};
  f32x4 acc2[4][4] = {};

  for (int kt = 0; kt < D_DIM / BK; ++kt) {
    const int kb = kt * BK;
#pragma unroll
    for (int i = 0; i < 4; ++i)
      gload_lds16(gA + (size_t)srow[i] * D_DIM + kb + scol[i], &As[0] + i * 2048 + wid * 512);
#pragma unroll
    for (int i = 0; i < 4; ++i)
      gload_lds16(gB1 + (size_t)srow[i] * D_DIM + kb + scol[i], &B1s[0] + i * 2048 + wid * 512);
#pragma unroll
    for (int i = 0; i < 4; ++i)
      gload_lds16(gB2 + (size_t)srow[i] * D_DIM + kb + scol[i], &B2s[0] + i * 2048 + wid * 512);
    __syncthreads();  // compiler emits vmcnt(0) drain before s_barrier
#pragma unroll
    for (int kk = 0; kk < 2; ++kk) {
      bf16x8 af[4], b1f[4], b2f[4];
#pragma unroll
      for (int f = 0; f < 4; ++f)
        af[f] = *(const bf16x8*)((const char*)As + (aOff[f] ^ (kk << 6)));
#pragma unroll
      for (int f = 0; f < 4; ++f)
        b1f[f] = *(const bf16x8*)((const char*)B1s + (bOff[f] ^ (kk << 6)));
#pragma unroll
      for (int f = 0; f < 4; ++f)
        b2f[f] = *(const bf16x8*)((const char*)B2s + (bOff[f] ^ (kk << 6)));
#pragma unroll
      for (int mf = 0; mf < 4; ++mf)
#pragma unroll
        for (int nf = 0; nf < 4; ++nf) {
          acc1[mf][nf] = __builtin_amdgcn_mfma_f32_16x16x32_bf16(af[mf], b1f[nf], acc1[mf][nf], 0, 0, 0);
          acc2[mf][nf] = __builtin_amdgcn_mfma_f32_16x16x32_bf16(af[mf], b2f[nf], acc2[mf][nf], 0, 0, 0);
        }
    }
    __syncthreads();
  }

  // epilogue: C/D layout col=lane&15, row=(lane>>4)*4+r  [m89]
#pragma unroll
  for (int mf = 0; mf < 4; ++mf) {
    const int mbase = row0 + wm * 64 + mf * 16 + lk * 4;
#pragma unroll
    for (int nf = 0; nf < 4; ++nf) {
      const int ncol = n0 + wn * 64 + nf * 16 + l15;
#pragma unroll
      for (int r = 0; r < 4; ++r) {
        const float a = acc1[mf][nf][r];
        const float b = acc2[mf][nf][r];
        const float hv = (a / (1.f + __expf(-a))) * b;
        hbuf[(size_t)(mbase + r) * H_DIM + ncol] = f2bf(hv);
      }
    }
  }
}

// ---------------- grouped GEMM2: part[t][slot] = h @ w2^T -------------------
__global__ __launch_bounds__(256, 2) void gemm2_kernel(
    const unsigned short* __restrict__ hbuf, const unsigned short* __restrict__ wb2,
    unsigned short* __restrict__ part, const int* __restrict__ perm_token,
    const int* __restrict__ perm_slot, const int* __restrict__ tile_e,
    const int* __restrict__ tile_row0, const int* __restrict__ nMt) {
  if ((int)blockIdx.x >= *nMt) return;
  __shared__ unsigned short As[BM * BK];
  __shared__ unsigned short Bs[BN * BK];

  const int e = tile_e[blockIdx.x];
  const int row0 = tile_row0[blockIdx.x];
  const int n0 = blockIdx.y * BN;

  const int tid = threadIdx.x;
  const int lane = tid & 63, wid = tid >> 6;
  const int wm = wid >> 1, wn = wid & 1;
  const int l15 = lane & 15, lk = lane >> 4;

  int srow[4], scol[4];
#pragma unroll
  for (int i = 0; i < 4; ++i) {
    const int fo = i * 4096 + wid * 1024 + lane * 16;
    const int r = fo >> 7;
    const int cbl = (fo & 127) ^ ((r & 7) << 4);
    srow[i] = r; scol[i] = cbl >> 1;
  }
  const unsigned short* gA = hbuf + (size_t)row0 * H_DIM;
  const unsigned short* gB = wb2 + ((size_t)e * D_DIM + n0) * H_DIM;

  int aOff[4], bOff[4];
#pragma unroll
  for (int f = 0; f < 4; ++f) {
    const int ra = wm * 64 + f * 16 + l15, sa = (ra & 7) << 4;
    aOff[f] = ra * 128 + ((lk * 16) ^ (sa & 0x30)) + (sa & 0x40);
    const int rb = wn * 64 + f * 16 + l15, sb = (rb & 7) << 4;
    bOff[f] = rb * 128 + ((lk * 16) ^ (sb & 0x30)) + (sb & 0x40);
  }

  f32x4 acc[4][4] = {};

  for (int kt = 0; kt < H_DIM / BK; ++kt) {
    const int kb = kt * BK;
#pragma unroll
    for (int i = 0; i < 4; ++i)
      gload_lds16(gA + (size_t)srow[i] * H_DIM + kb + scol[i], &As[0] + i * 2048 + wid * 512);
#pragma unroll
    for (int i = 0; i < 4; ++i)
      gload_lds16(gB + (size_t)srow[i] * H_DIM + kb + scol[i], &Bs[0] + i * 2048 + wid * 512);
    __syncthreads();
#pragma unroll
    for (int kk = 0; kk < 2; ++kk) {
      bf16x8 af[4], bf[4];
#pragma unroll
      for (int f = 0; f < 4; ++f)
        af[f] = *(const bf16x8*)((const char*)As + (aOff[f] ^ (kk << 6)));
#pragma unroll
      for (int f = 0; f < 4; ++f)
        bf[f] = *(const bf16x8*)((const char*)Bs + (bOff[f] ^ (kk << 6)));
#pragma unroll
      for (int mf = 0; mf < 4; ++mf)
#pragma unroll
        for (int nf = 0; nf < 4; ++nf)
          acc[mf][nf] = __builtin_amdgcn_mfma_f32_16x16x32_bf16(af[mf], bf[nf], acc[mf][nf], 0, 0, 0);
    }
    __syncthreads();
  }

#pragma unroll
  for (int mf = 0; mf < 4; ++mf) {
    const int mbase = row0 + wm * 64 + mf * 16 + lk * 4;
#pragma unroll
    for (int r = 0; r < 4; ++r) {
      const int p = mbase + r;
      const int t = perm_token[p];
      if (t < 0) continue;
      const int sl = perm_slot[p];
      unsigned short* dst = part + ((size_t)t * 2 + sl) * D_DIM;
#pragma unroll
      for (int nf = 0; nf < 4; ++nf) {
        const int ncol = n0 + wn * 64 + nf * 16 + l15;
        dst[ncol] = f2bf(acc[mf][nf][r]);
      }
    }
  }
}

// ---------------- combine: out[t] = part[t][0] + part[t][1] ----------------
__global__ __launch_bounds__(256) void combine_kernel(const unsigned short* __restrict__ part,
                                                      float* __restrict__ out) {
  const int stride = gridDim.x * blockDim.x;
  const int total8 = T_TOK * (D_DIM / 8);
  for (int i = blockIdx.x * blockDim.x + threadIdx.x; i < total8; i += stride) {
    const int t = i >> 8;           // D_DIM/8 = 256 chunks per token
    const int dc = (i & 255) * 8;
    const uint4 a = *(const uint4*)(part + ((size_t)t * 2 + 0) * D_DIM + dc);
    const uint4 b = *(const uint4*)(part + ((size_t)t * 2 + 1) * D_DIM + dc);
    float4 r0, r1;
    r0.x = bf2f(a.x & 0xffff) + bf2f(b.x & 0xffff);
    r0.y = bf2f(a.x >> 16)    + bf2f(b.x >> 16);
    r0.z = bf2f(a.y & 0xffff) + bf2f(b.y & 0xffff);
    r0.w = bf2f(a.y >> 16)    + bf2f(b.y >> 16);
    r1.x = bf2f(a.z & 0xffff) + bf2f(b.z & 0xffff);
    r1.y = bf2f(a.z >> 16)    + bf2f(b.z >> 16);
    r1.z = bf2f(a.w & 0xffff) + bf2f(b.w & 0xffff);
    r1.w = bf2f(a.w >> 16)    + bf2f(b.w >> 16);
    float4* o = (float4*)(out + (size_t)t * D_DIM + dc);
    o[0] = r0; o[1] = r1;
  }
}

// ---------------- host launch ----------------
extern "C" void kernel_launch(void* const* d_in, const int* in_sizes, int n_in,
                              void* d_out, int out_size, void* d_ws, size_t ws_size,
                              hipStream_t stream) {
  const float* x = (const float*)d_in[0];
  const float* gate_w = (const float*)d_in[1];
  const float* w1 = (const float*)d_in[2];
  const float* w2 = (const float*)d_in[3];
  const float* w3 = (const float*)d_in[4];
  float* out = (float*)d_out;

  // workspace carve-up (~392 MB total)
  char* ws = (char*)d_ws;
  size_t off = 0;
  auto alloc = [&](size_t bytes) -> void* {
    off = (off + 255) & ~(size_t)255;
    void* p = ws + off;
    off += bytes;
    return p;
  };
  unsigned short* wb1 = (unsigned short*)alloc((size_t)NEXP * H_DIM * D_DIM * 2);
  unsigned short* wb3 = (unsigned short*)alloc((size_t)NEXP * H_DIM * D_DIM * 2);
  unsigned short* wb2 = (unsigned short*)alloc((size_t)NEXP * D_DIM * H_DIM * 2);
  unsigned short* xg   = (unsigned short*)alloc((size_t)MAXSLOTS * D_DIM * 2);
  unsigned short* hbuf = (unsigned short*)alloc((size_t)MAXSLOTS * H_DIM * 2);
  unsigned short* part = (unsigned short*)alloc((size_t)T_TOK * 2 * D_DIM * 2);
  int* top_idx = (int*)alloc((size_t)T_TOK * 2 * 4);
  float* top_score = (float*)alloc((size_t)T_TOK * 2 * 4);
  int* perm_token = (int*)alloc((size_t)MAXSLOTS * 4);
  float* perm_score = (float*)alloc((size_t)MAXSLOTS * 4);
  int* perm_slot = (int*)alloc((size_t)MAXSLOTS * 4);
  int* ctr = (int*)alloc(16 * 4);        // [0..7]=cnt, [8..15]=cursor
  int* seg_off = (int*)alloc(NEXP * 4);
  int* tile_e = (int*)alloc(MAXMT * 4);
  int* tile_row0 = (int*)alloc(MAXMT * 4);
  int* nMt = (int*)alloc(4);
  int* cnt = ctr;
  int* cursor = ctr + 8;

  const int n8 = NEXP * H_DIM * D_DIM / 8;

  hipLaunchKernelGGL(init_kernel, dim3(MAXSLOTS / 256), dim3(256), 0, stream, perm_token, ctr);
  hipLaunchKernelGGL(router_kernel, dim3(T_TOK / 16), dim3(256), 0, stream,
                     x, gate_w, top_idx, top_score, cnt);
  hipLaunchKernelGGL(offsets_kernel, dim3(1), dim3(64), 0, stream,
                     cnt, seg_off, tile_e, tile_row0, nMt);
  hipLaunchKernelGGL(assign_kernel, dim3(T_TOK / 256), dim3(256), 0, stream,
                     top_idx, top_score, seg_off, cursor, perm_token, perm_score, perm_slot);
  hipLaunchKernelGGL(gather_kernel, dim3(MAXSLOTS), dim3(256), 0, stream,
                     x, perm_token, perm_score, xg);
  hipLaunchKernelGGL(wconv_kernel, dim3(2048), dim3(256), 0, stream, w1, wb1, n8);
  hipLaunchKernelGGL(wconv_kernel, dim3(2048), dim3(256), 0, stream, w3, wb3, n8);
  hipLaunchKernelGGL(wconv_kernel, dim3(2048), dim3(256), 0, stream, w2, wb2, n8);
  hipLaunchKernelGGL(gemm1_kernel, dim3(MAXMT, H_DIM / BN), dim3(256), 0, stream,
                     xg, wb1, wb3, hbuf, tile_e, tile_row0, nMt);
  hipLaunchKernelGGL(gemm2_kernel, dim3(MAXMT, D_DIM / BN), dim3(256), 0, stream,
                     hbuf, wb2, part, perm_token, perm_slot, tile_e, tile_row0, nMt);
  hipLaunchKernelGGL(combine_kernel, dim3(2048), dim3(256), 0, stream, part, out);
}